// Round 9
// baseline (2437.635 us; speedup 1.0000x reference)
//
#include <hip/hip_runtime.h>

// SurvModel: x=relu(BN(in@W1+b1)); h=tanh(BN(x@Watt1+batt1)); s=h@Watt2+batt2;
// A=softmax_N(s); top64 by A desc (stable); zs=x[top]*softmax(A[top]);
// zq/zk/zv=zs@W*; zw=softmax(zq@zk^T)@zv; out=relu(zw.flat@Wz+bz)@Wf+bf.
// R9: lockstep gl_lds (compiler-proof schedule) + DEPTH-2 prefetch, triple buf:
// stage kc+2, vmcnt(12) waits only for loads issued 2 iters (~3200cy) ago >> 900cy
// HBM latency. 72KB LDS (3 x [A 16K fp32 + B 8K bf16]) -> 2 blk/CU. Plain-bf16
// scores + 24-bin margin + exact fp32 rescore of ~70 candidates (R8-validated).

#define NN   131072
#define DIN  768
#define DH   128
#define DA   32

using f32x4  = __attribute__((ext_vector_type(4))) float;
using bf16x8 = __attribute__((ext_vector_type(8))) __bf16;

// workspace byte offsets
#define WS_S      0            // float[131072] approx scores
#define WS_PZ8    524288       // float[8192]
#define WS_HIST   557056       // int[4096]
#define WS_MISC   573440       // [0]=Z f32, [2]=cnt int, [3]=bstar int
#define WS_CIDX   573504       // int[512]
#define WS_CS     575552       // float[512]
#define WS_ORDER  577600       // int[64]
#define WS_W      577856       // float[64]
#define WS_ZQ     578112       // float[2048]
#define WS_ZK     586304       // float[2048]
#define WS_ZV     594496       // float[2048]
#define WS_ZW     602688       // float[2048]
#define WS_W1T    610944       // 24*8192 B bf16 W1, [kc][col][kg] frag layout

__device__ __forceinline__ int s_bin(float s) {
  int b = (int)((s + 6.0f) * (4096.0f / 12.0f));
  return b < 0 ? 0 : (b > 4095 ? 4095 : b);
}

__device__ __forceinline__ void gl_lds16(const void* g, void* l) {
  __builtin_amdgcn_global_load_lds(
      (const __attribute__((address_space(1))) void*)g,
      (__attribute__((address_space(3))) void*)l, 16, 0, 0);
}

// K0: W1 -> bf16, [kc][col][kg]: 16B unit = bf16(W1[kc*32+kg*8+j][col]). Zero hist.
__global__ void k_prep(const float* __restrict__ W1, char* __restrict__ ws) {
  int T = blockIdx.x * 256 + threadIdx.x;       // grid 48*256 = 12288
  if (T < 4112) ((int*)(ws + WS_HIST))[T] = 0;
  int kg = T & 3, col = (T >> 2) & 127, kc = T >> 9;
  bf16x8 ov;
  #pragma unroll
  for (int j = 0; j < 8; ++j)
    ov[j] = (__bf16)W1[(size_t)(kc * 32 + kg * 8 + j) * 128 + col];
  *(bf16x8*)(ws + WS_W1T + (size_t)kc * 8192 + col * 64 + kg * 16) = ov;
}

// ---------------- K1: main GEMM (plain bf16) + h + approx scores ----------------
__global__ __launch_bounds__(256, 2) void k_main(
    const float* __restrict__ inp,
    const float* __restrict__ b1, const float* __restrict__ g1, const float* __restrict__ be1,
    const float* __restrict__ Watt1, const float* __restrict__ batt1,
    const float* __restrict__ g2, const float* __restrict__ be2,
    const float* __restrict__ Watt2, const float* __restrict__ batt2,
    char* __restrict__ ws)
{
  // LDS 72K: A bufs 3x16K at 0/16K/32K; B bufs 3x8K at 48K/56K/64K.
  // Phase 2 reuses [0,32K) x-half fp32 + [32K,48K) Watt1.
  __shared__ __align__(16) char lds[73728];
  float* s_out = (float*)(ws + WS_S);
  float* pz8   = (float*)(ws + WS_PZ8);
  int*   hist  = (int*)(ws + WS_HIST);

  const int t = threadIdx.x;
  const int l = t & 63;
  const int wid = t >> 6;                  // wave rows: wid*32 .. +32 (all 128 cols)
  const int r15 = l & 15, kg = l >> 4;
  const int blockRow = blockIdx.x * 128;
  const float inv = 1.0f / sqrtf(1.0f + 1e-5f);

  char* xh  = lds;
  float* wat = (float*)(lds + 32768);

  // staging: A source-preswizzled (rule #21), B plain frag-ready copy
  const int sr = t >> 3;                   // 0..31
  const int su = (t & 7) ^ (sr & 7);
  const float* aSrc = inp + (size_t)(blockRow + sr) * DIN + su * 4;
  const char*  bSrc = ws + WS_W1T + t * 16;

  f32x4 acc[2][8];
  #pragma unroll
  for (int i = 0; i < 2; ++i)
    #pragma unroll
    for (int j = 0; j < 8; ++j)
      #pragma unroll
      for (int q = 0; q < 4; ++q) acc[i][j][q] = 0.0f;

#define STAGE(buf3, kc_) do { \
    char* Ab_ = lds + (buf3) * 16384; \
    char* Bb_ = lds + 49152 + (buf3) * 8192; \
    _Pragma("unroll") \
    for (int c = 0; c < 4; ++c) \
      gl_lds16(aSrc + (size_t)c * 24576 + (kc_) * 32, Ab_ + c * 4096 + t * 16); \
    _Pragma("unroll") \
    for (int c = 0; c < 2; ++c) \
      gl_lds16(bSrc + (size_t)(kc_) * 8192 + c * 4096, Bb_ + c * 4096 + t * 16); \
  } while (0)

#define WAITN(n) asm volatile("s_waitcnt vmcnt(" #n ")" ::: "memory")
#define SB __builtin_amdgcn_sched_barrier(0)
#define BAR __builtin_amdgcn_s_barrier()

#define COMP(buf3) do { \
    const char* A_ = lds + (buf3) * 16384; \
    const char* B_ = lds + 49152 + (buf3) * 8192; \
    bf16x8 af0, af1; \
    { int R = wid * 32 + r15; \
      const char* base = A_ + R * 128; int sw = R & 7; \
      f32x4 x0 = *(const f32x4*)(base + (((2 * kg)     ^ sw) << 4)); \
      f32x4 x1 = *(const f32x4*)(base + (((2 * kg + 1) ^ sw) << 4)); \
      _Pragma("unroll") \
      for (int j = 0; j < 4; ++j) { af0[j] = (__bf16)x0[j]; af0[4 + j] = (__bf16)x1[j]; } } \
    { int R = wid * 32 + 16 + r15; \
      const char* base = A_ + R * 128; int sw = R & 7; \
      f32x4 x0 = *(const f32x4*)(base + (((2 * kg)     ^ sw) << 4)); \
      f32x4 x1 = *(const f32x4*)(base + (((2 * kg + 1) ^ sw) << 4)); \
      _Pragma("unroll") \
      for (int j = 0; j < 4; ++j) { af1[j] = (__bf16)x0[j]; af1[4 + j] = (__bf16)x1[j]; } } \
    _Pragma("unroll") \
    for (int ni = 0; ni < 8; ++ni) { \
      bf16x8 bf_ = *(const bf16x8*)(B_ + (ni * 16 + r15) * 64 + kg * 16); \
      acc[0][ni] = __builtin_amdgcn_mfma_f32_16x16x32_bf16(af0, bf_, acc[0][ni], 0, 0, 0); \
      acc[1][ni] = __builtin_amdgcn_mfma_f32_16x16x32_bf16(af1, bf_, acc[1][ni], 0, 0, 0); \
    } \
  } while (0)

  STAGE(0, 0); STAGE(1, 1);
  #pragma unroll 1
  for (int kc3 = 0; kc3 < 7; ++kc3) {
    const int kc = kc3 * 3;
    STAGE(2, kc + 2); WAITN(12); SB; BAR; SB; COMP(0); SB; BAR; SB;
    STAGE(0, kc + 3); WAITN(12); SB; BAR; SB; COMP(1); SB; BAR; SB;
    STAGE(1, kc + 4); WAITN(12); SB; BAR; SB; COMP(2); SB; BAR; SB;
  }
  // kc = 21, 22, 23
  STAGE(2, 23); WAITN(12); SB; BAR; SB; COMP(0); SB; BAR; SB;
  WAITN(6);  SB; BAR; SB; COMP(1); SB; BAR; SB;
  WAITN(0);  SB; BAR; SB; COMP(2); SB; BAR; SB;
#undef COMP
#undef STAGE

  __syncthreads();
  // Watt1 -> [32K,48K)
  #pragma unroll
  for (int c = 0; c < 4; ++c)
    gl_lds16(Watt1 + c * 1024 + t * 4, (char*)wat + c * 4096 + t * 16);
  WAITN(0);
  __syncthreads();

  // phase 2 in two 64-row halves: BN+relu -> x-half fp32; h/tanh/score per half
  const int row = t >> 2, q4 = t & 3;          // 64 rows, 4 threads/row, 8 a-dims
  const int rsw = (row & 31) << 4;
  for (int pass = 0; pass < 2; ++pass) {
    if ((wid >> 1) == pass) {
      #pragma unroll
      for (int ni = 0; ni < 8; ++ni) {
        int col = ni * 16 + r15;
        float b1c = b1[col], s1c = g1[col] * inv, be1c = be1[col];
        #pragma unroll
        for (int mi = 0; mi < 2; ++mi) {
          #pragma unroll
          for (int q = 0; q < 4; ++q) {
            int rloc = (wid & 1) * 32 + mi * 16 + kg * 4 + q;
            float xv = fmaxf((acc[mi][ni][q] + b1c) * s1c + be1c, 0.0f);
            *(float*)(xh + rloc * 512 + ((col * 4) ^ ((rloc & 31) << 4))) = xv;
          }
        }
      }
    }
    __syncthreads();
    float hacc[8];
    #pragma unroll
    for (int a = 0; a < 8; ++a) hacc[a] = 0.0f;
    const char* xrow = xh + row * 512;
    const float* watt = wat + q4 * 8;
    for (int cb = 0; cb < 128; cb += 4) {
      f32x4 xv = *(const f32x4*)(xrow + ((cb * 4) ^ rsw));
      #pragma unroll
      for (int u = 0; u < 4; ++u) {
        const float* wrow = watt + (cb + u) * 32;
        f32x4 w0 = *(const f32x4*)(wrow);
        f32x4 w1 = *(const f32x4*)(wrow + 4);
        float xs = xv[u];
        #pragma unroll
        for (int q = 0; q < 4; ++q) {
          hacc[q]     += xs * w0[q];
          hacc[4 + q] += xs * w1[q];
        }
      }
    }
    float partial = 0.0f;
    #pragma unroll
    for (int a = 0; a < 8; ++a) {
      int ai = q4 * 8 + a;
      float hv = tanhf((hacc[a] + batt1[ai]) * (g2[ai] * inv) + be2[ai]);
      partial += hv * Watt2[ai];
    }
    partial += __shfl_xor(partial, 1, 64);
    partial += __shfl_xor(partial, 2, 64);
    float ev = 0.0f;
    if (q4 == 0) {
      float sv = partial + batt2[0];
      s_out[blockRow + pass * 64 + row] = sv;
      atomicAdd(&hist[s_bin(sv)], 1);
      ev = expf(sv);
    }
    #pragma unroll
    for (int off = 32; off >= 1; off >>= 1) ev += __shfl_xor(ev, off, 64);
    if (l == 0) pz8[blockIdx.x * 8 + pass * 4 + wid] = ev;
    __syncthreads();
  }
#undef WAITN
#undef SB
#undef BAR
}

// ---------------- K2: Z reduce + histogram threshold (with margin) ------------
__global__ void k_reduce(char* __restrict__ ws) {
  float* pz8 = (float*)(ws + WS_PZ8);
  int* hist = (int*)(ws + WS_HIST);
  float* miscf = (float*)(ws + WS_MISC);
  int* misci = (int*)(ws + WS_MISC);
  const int t = threadIdx.x;
  __shared__ float red[256];
  __shared__ int csum[256];
  float z = 0.0f;
  for (int i = t; i < 8192; i += 256) z += pz8[i];
  red[t] = z;
  int c = 0;
  #pragma unroll
  for (int u = 0; u < 16; ++u) c += hist[t * 16 + u];
  csum[t] = c;
  __syncthreads();
  for (int off = 128; off >= 1; off >>= 1) {
    if (t < off) red[t] += red[t + off];
    __syncthreads();
  }
  if (t == 0) {
    miscf[0] = red[0];
    int cum = 0, bstar = 0;
    for (int ch = 255; ch >= 0; --ch) {
      if (cum + csum[ch] >= 64) {
        for (int b = ch * 16 + 15; b >= ch * 16; --b) {
          cum += hist[b];
          if (cum >= 64) { bstar = b; break; }
        }
        break;
      }
      cum += csum[ch];
    }
    // margin: 24 bins = 0.07 in s, >> bf16-GEMM score error ~5e-3
    misci[3] = (bstar > 24) ? bstar - 24 : 0;
    misci[2] = 0;
  }
}

// ---------------- K3: gather candidates ----------------
__global__ void k_gather(char* __restrict__ ws) {
  const int i = blockIdx.x * 256 + threadIdx.x;
  float* s_out = (float*)(ws + WS_S);
  int* misci = (int*)(ws + WS_MISC);
  int* cidx = (int*)(ws + WS_CIDX);
  float* cs = (float*)(ws + WS_CS);
  float s = s_out[i];
  if (s_bin(s) >= misci[3]) {
    int pos = atomicAdd(&misci[2], 1);
    if (pos < 512) { cidx[pos] = i; cs[pos] = s; }
  }
}

// ---------------- K3b: EXACT fp32 rescore of candidates ----------------------
__global__ void k_exact(const float* __restrict__ inp, const float* __restrict__ W1,
                        const float* __restrict__ b1, const float* __restrict__ g1,
                        const float* __restrict__ be1,
                        const float* __restrict__ Watt1, const float* __restrict__ batt1,
                        const float* __restrict__ g2, const float* __restrict__ be2,
                        const float* __restrict__ Watt2, const float* __restrict__ batt2,
                        char* __restrict__ ws)
{
  int* misci = (int*)(ws + WS_MISC);
  int* cidx = (int*)(ws + WS_CIDX);
  float* cs = (float*)(ws + WS_CS);
  const int b = blockIdx.x, t = threadIdx.x;
  int cnt = misci[2]; if (cnt > 512) cnt = 512;
  if (b >= cnt) return;
  __shared__ float rowS[768];
  __shared__ float xS[128];
  __shared__ float hS[32];
  const float inv = 1.0f / sqrtf(1.0f + 1e-5f);
  const int r = cidx[b];
  for (int i = t; i < 768; i += 256) rowS[i] = inp[(size_t)r * 768 + i];
  __syncthreads();
  {
    int col = t >> 1, half = t & 1;
    float d = 0.0f;
    for (int k = half * 384; k < half * 384 + 384; ++k) d += rowS[k] * W1[(size_t)k * 128 + col];
    d += __shfl_xor(d, 1, 64);
    if (half == 0) xS[col] = fmaxf((d + b1[col]) * (g1[col] * inv) + be1[col], 0.0f);
  }
  __syncthreads();
  if (t < 64) {
    int a = t >> 1, half = t & 1;
    float d = 0.0f;
    for (int c = half * 64; c < half * 64 + 64; ++c) d += xS[c] * Watt1[c * 32 + a];
    d += __shfl_xor(d, 1, 64);
    if (half == 0) hS[a] = tanhf((d + batt1[a]) * (g2[a] * inv) + be2[a]);
  }
  __syncthreads();
  if (t == 0) {
    float s = 0.0f;
    for (int a = 0; a < 32; ++a) s += hS[a] * Watt2[a];
    cs[b] = s + batt2[0];
  }
}

// ---------------- K4: sort candidates by EXACT s, top-64 + weights ------------
__global__ void k_select(char* __restrict__ ws) {
  const int t = threadIdx.x;
  int* misci = (int*)(ws + WS_MISC);
  float* miscf = (float*)(ws + WS_MISC);
  int* cidx = (int*)(ws + WS_CIDX);
  float* cs = (float*)(ws + WS_CS);
  int* order = (int*)(ws + WS_ORDER);
  float* wsel = (float*)(ws + WS_W);
  __shared__ unsigned long long keys[512];
  __shared__ float aLds[64];
  int cnt = misci[2]; if (cnt > 512) cnt = 512;
  for (int i = t; i < 512; i += 256) {
    unsigned long long kkey = 0xFFFFFFFFFFFFFFFFull;
    if (i < cnt) {
      unsigned u = __float_as_uint(cs[i]);
      u = (u & 0x80000000u) ? ~u : (u | 0x80000000u);  // ascending map
      unsigned du = ~u;                                 // descending by s
      kkey = ((unsigned long long)du << 32) | (unsigned)cidx[i];  // tie: idx asc
    }
    keys[i] = kkey;
  }
  __syncthreads();
  for (int k = 2; k <= 512; k <<= 1) {
    for (int j = k >> 1; j > 0; j >>= 1) {
      for (int i = t; i < 512; i += 256) {
        int ixj = i ^ j;
        if (ixj > i) {
          bool up = ((i & k) == 0);
          unsigned long long a = keys[i], b2 = keys[ixj];
          if (up ? (a > b2) : (a < b2)) { keys[i] = b2; keys[ixj] = a; }
        }
      }
      __syncthreads();
    }
  }
  float Z = miscf[0];
  if (t < 64) {
    unsigned du = (unsigned)(keys[t] >> 32);
    unsigned m = ~du;                       // undo descending map
    float sx = (m & 0x80000000u) ? __uint_as_float(m & 0x7fffffffu)
                                 : __uint_as_float(~m);
    order[t] = (int)(keys[t] & 0xFFFFFFFFull);
    aLds[t] = expf(sx) / Z;                 // exact s, approx Z (insensitive)
  }
  __syncthreads();
  if (t < 64) {
    float m = aLds[0];                      // sorted desc -> max
    float e = expf(aLds[t] - m);
    float sum = e;
    #pragma unroll
    for (int off = 32; off >= 1; off >>= 1) sum += __shfl_xor(sum, off, 64);
    wsel[t] = e / sum;
  }
}

// ---------------- K5: recompute x for top-64, zs, zq/zk/zv ----------------
__global__ void k_zs(const float* __restrict__ inp, const float* __restrict__ W1,
                     const float* __restrict__ b1, const float* __restrict__ g1, const float* __restrict__ be1,
                     const float* __restrict__ Wq, const float* __restrict__ Wk, const float* __restrict__ Wv,
                     char* __restrict__ ws)
{
  const int t = threadIdx.x, b = blockIdx.x;
  int* order = (int*)(ws + WS_ORDER);
  float* wsel = (float*)(ws + WS_W);
  float* zq = (float*)(ws + WS_ZQ);
  float* zk = (float*)(ws + WS_ZK);
  float* zv = (float*)(ws + WS_ZV);
  __shared__ float rowS[768];
  __shared__ float zsS[128];
  const float inv = 1.0f / sqrtf(1.0f + 1e-5f);
  int r = order[b];
  float wgt = wsel[b];
  for (int i = t; i < 768; i += 256) rowS[i] = inp[(size_t)r * 768 + i];
  __syncthreads();
  {
    int col = t >> 1, half = t & 1;
    float d = 0.0f;
    for (int k = half * 384; k < half * 384 + 384; ++k) d += rowS[k] * W1[(size_t)k * 128 + col];
    d += __shfl_xor(d, 1, 64);
    if (half == 0) {
      float x = fmaxf((d + b1[col]) * (g1[col] * inv) + be1[col], 0.0f);
      zsS[col] = x * wgt;
    }
  }
  __syncthreads();
  if (t < 96) {
    int which = t >> 5, a = t & 31;
    const float* W = (which == 0) ? Wq : ((which == 1) ? Wk : Wv);
    float d = 0.0f;
    for (int c = 0; c < 128; ++c) d += zsS[c] * W[c * 32 + a];
    float* dst = (which == 0) ? zq : ((which == 1) ? zk : zv);
    dst[b * 32 + a] = d;
  }
}

// ---------------- K6a: 64x64 attention (also zeroes d_out for K6b atomics) ----
__global__ void k_attn(char* __restrict__ ws, float* __restrict__ out) {
  const int t = threadIdx.x;
  if (t == 0) out[0] = 0.0f;
  float* zq = (float*)(ws + WS_ZQ);
  float* zk = (float*)(ws + WS_ZK);
  float* zv = (float*)(ws + WS_ZV);
  float* zw = (float*)(ws + WS_ZW);
  __shared__ float q[2048], kk[2048], v[2048], P[4096];
  for (int i = t; i < 2048; i += 256) { q[i] = zq[i]; kk[i] = zk[i]; v[i] = zv[i]; }
  __syncthreads();
  for (int o = t; o < 4096; o += 256) {
    int i = o >> 6, j = o & 63;
    float d = 0.0f;
    for (int a = 0; a < 32; ++a) d += q[i * 32 + a] * kk[j * 32 + a];
    P[o] = d;
  }
  __syncthreads();
  if (t < 64) {
    float m = -1e30f;
    for (int j = 0; j < 64; ++j) m = fmaxf(m, P[t * 64 + j]);
    float sum = 0.0f;
    for (int j = 0; j < 64; ++j) { float e = expf(P[t * 64 + j] - m); P[t * 64 + j] = e; sum += e; }
    float rs = 1.0f / sum;
    for (int j = 0; j < 64; ++j) P[t * 64 + j] *= rs;
  }
  __syncthreads();
  for (int o = t; o < 2048; o += 256) {
    int i = o >> 5, a = o & 31;
    float d = 0.0f;
    for (int j = 0; j < 64; ++j) d += P[i * 64 + j] * v[j * 32 + a];
    zw[o] = d;
  }
}

// ---------------- K6b: zw.flat @ Wz + bz, relu, dot Wf, atomic out -----------
__global__ void k_wz(const float* __restrict__ Wz, const float* __restrict__ bz,
                     const float* __restrict__ Wf, const float* __restrict__ bf_,
                     char* __restrict__ ws, float* __restrict__ out) {
  const int t = threadIdx.x, j = blockIdx.x;
  float* zw = (float*)(ws + WS_ZW);
  __shared__ float red[256];
  float p = 0.0f;
  for (int i2 = t; i2 < 2048; i2 += 256) p += zw[i2] * Wz[(size_t)i2 * 128 + j];
  red[t] = p; __syncthreads();
  for (int off = 128; off >= 1; off >>= 1) {
    if (t < off) red[t] += red[t + off];
    __syncthreads();
  }
  if (t == 0) {
    float o = fmaxf(red[0] + bz[j], 0.0f);
    float contrib = o * Wf[j] + (j == 0 ? bf_[0] : 0.0f);
    atomicAdd(out, contrib);
  }
}

extern "C" void kernel_launch(void* const* d_in, const int* in_sizes, int n_in,
                              void* d_out, int out_size, void* d_ws, size_t ws_size,
                              hipStream_t stream) {
  const float* inp   = (const float*)d_in[0];
  const float* W1    = (const float*)d_in[1];
  const float* b1    = (const float*)d_in[2];
  const float* g1    = (const float*)d_in[3];
  const float* be1   = (const float*)d_in[4];
  const float* Watt1 = (const float*)d_in[5];
  const float* batt1 = (const float*)d_in[6];
  const float* g2    = (const float*)d_in[7];
  const float* be2   = (const float*)d_in[8];
  const float* Watt2 = (const float*)d_in[9];
  const float* batt2 = (const float*)d_in[10];
  const float* Wq    = (const float*)d_in[11];
  const float* Wk    = (const float*)d_in[12];
  const float* Wv    = (const float*)d_in[13];
  const float* Wz    = (const float*)d_in[14];
  const float* bz    = (const float*)d_in[15];
  const float* Wf    = (const float*)d_in[16];
  const float* bf_   = (const float*)d_in[17];
  char* ws = (char*)d_ws;

  k_prep<<<dim3(48), dim3(256), 0, stream>>>(W1, ws);
  k_main<<<dim3(1024), dim3(256), 0, stream>>>(inp, b1, g1, be1, Watt1, batt1, g2, be2, Watt2, batt2, ws);
  k_reduce<<<dim3(1), dim3(256), 0, stream>>>(ws);
  k_gather<<<dim3(512), dim3(256), 0, stream>>>(ws);
  k_exact<<<dim3(512), dim3(256), 0, stream>>>(inp, W1, b1, g1, be1, Watt1, batt1, g2, be2, Watt2, batt2, ws);
  k_select<<<dim3(1), dim3(256), 0, stream>>>(ws);
  k_zs<<<dim3(64), dim3(256), 0, stream>>>(inp, W1, b1, g1, be1, Wq, Wk, Wv, ws);
  k_attn<<<dim3(1), dim3(256), 0, stream>>>(ws, (float*)d_out);
  k_wz<<<dim3(128), dim3(256), 0, stream>>>(Wz, bz, Wf, bf_, ws, (float*)d_out);
}